// Round 6
// baseline (1012.430 us; speedup 1.0000x reference)
//
#include <hip/hip_runtime.h>
#include <math.h>

// VGAE forward: 3x GCNConv + reparameterize.
// Pipeline (6 dispatches): MFMA GEMM1 (zeroes bcur) -> bucket-sort CSR build
//   (k_bucket fixed-stride + k_fill2) -> agg1(+b1,relu,f16) -> MFMA GEMM2
//   (W_mu|W_lv fused) -> agg2 (f32 mu/lv + fused z).
// R6: k_agg 16B-lane gather; z fused into agg2. R7(rev): seg-blocking by
//     DEST cannot beat the NXCD x |F| refetch floor (measured 203-207MB).
// R9: 6 dispatches (fixed-stride buckets, GEMM1 zeroes bcur, per-edge dis).
// R10: feature-panel partitioning to break the NXCD x |F| floor. F stored
//     panel-major [8][N][16] (32B rows). Agg blocks with blockIdx%8==p
//     process ONLY panel p; with round-robin block->XCD dispatch (same
//     mapping that yields the measured +10% XCD swizzle, m157/m192) each
//     XCD's gather working set is 3.2MB -> L2-resident. srcs/rowse re-read
//     per panel via NT loads (stream, don't pollute). GEMM1 out panel16;
//     agg1 h panel16; GEMM2 reads panel16 A-frags, writes mu/lv-interleaved
//     panels (8 mu + 8 lv cols of same latent idx) so agg2 keeps z fused
//     (mu/lv pairing via shfl_xor 2). 16 edges/trip, f16x4 (8B) per lane.

#define SHIFT 9            // nodes per bucket = 512
#define EPB 2048           // edges per k_bucket block
#define BSTRIDE 12288      // recs/srcs slots per bucket (1.5x Poisson mean)
#define CAP 15104          // fill2 LDS srcs capacity
#define WNODES 32          // nodes per wave in k_agg

using f32x4 = __attribute__((ext_vector_type(4))) float;
using f32x2 = __attribute__((ext_vector_type(2))) float;
using f16x8 = __attribute__((ext_vector_type(8))) _Float16;
using f16x4 = __attribute__((ext_vector_type(4))) _Float16;
using f16x2 = __attribute__((ext_vector_type(2))) _Float16;

// Block-wide (256 thr) exclusive scan of one int per thread.
__device__ inline int scan256(int v, int* wsum) {
    __syncthreads();  // protect wsum reuse across calls
    int lane = threadIdx.x & 63, wid = threadIdx.x >> 6;
    int s = v;
#pragma unroll
    for (int d = 1; d < 64; d <<= 1) {
        int u = __shfl_up(s, d, 64);
        if (lane >= d) s += u;
    }
    if (lane == 63) wsum[wid] = s;
    __syncthreads();
    int off = 0;
    for (int w = 0; w < wid; w++) off += wsum[w];
    return off + s - v;
}

// Bin EPB edges into LDS by bucket, burst-write packed (row<<9)|(col&511)
// records into the bucket's fixed-stride region (base = b*BSTRIDE + atomic
// cursor). Two passes over the (L2-hot) chunk; per-wave histograms+cursors.
__global__ __launch_bounds__(256) void k_bucket(const int* __restrict__ rowi,
                                                const int* __restrict__ coli,
                                                int* __restrict__ bcur,
                                                int* __restrict__ recs,
                                                int E, int NB) {
    __shared__ int lh[4][256], lcur[4][256], excl[256], gbase[256], wsum[4];
    __shared__ int2 stage[EPB];
    int t = threadIdx.x, w = t >> 6;
    lh[0][t] = 0; lh[1][t] = 0; lh[2][t] = 0; lh[3][t] = 0;
    __syncthreads();
    int base = blockIdx.x * EPB;
    int nE = min(EPB, E - base);
    // pass A: per-wave histogram
    for (int i = t; i < nE; i += 256)
        atomicAdd(&lh[w][coli[base + i] >> SHIFT], 1);
    __syncthreads();
    int h0 = lh[0][t], h1 = lh[1][t], h2 = lh[2][t], h3 = lh[3][t];
    int tot = h0 + h1 + h2 + h3;
    int ex = scan256(tot, wsum);
    excl[t] = ex;
    lcur[0][t] = ex;
    lcur[1][t] = ex + h0;
    lcur[2][t] = ex + h0 + h1;
    lcur[3][t] = ex + h0 + h1 + h2;
    if (t < NB && tot)
        gbase[t] = t * BSTRIDE + atomicAdd(&bcur[t], tot);
    __syncthreads();
    // pass B: re-read (L2-hot) and scatter into LDS stage, per-wave cursors
    for (int i = t; i < nE; i += 256) {
        int r = rowi[base + i], c = coli[base + i];
        int p = atomicAdd(&lcur[w][c >> SHIFT], 1);
        stage[p] = make_int2(r, c);
    }
    __syncthreads();
    // pass C: coalesced burst write per bucket run (packed, bounds-guarded)
    for (int i = t; i < nE; i += 256) {
        int2 r = stage[i];
        int bb = r.y >> SHIFT;
        int idx = gbase[bb] + (i - excl[bb]);
        if (idx - bb * BSTRIDE < BSTRIDE)   // statistically never false
            recs[idx] = (r.x << SHIFT) | (r.y & 511);
    }
}

// One block per bucket: local histogram -> rowse (absolute spans) + dis,
// LDS scatter of rows, coalesced burst write of srcs (bucket-strided).
__global__ __launch_bounds__(256) void k_fill2(const int* __restrict__ recs,
                                               const int* __restrict__ bcur,
                                               int2* __restrict__ rowse,
                                               float* __restrict__ dis,
                                               int* __restrict__ srcs, int N) {
    __shared__ int hist[512], excl[512], wsum[4];
    __shared__ int srcsL[CAP];
    int t = threadIdx.x;
    int b = blockIdx.x;
    int nbase = b << SHIFT;
    int start = b * BSTRIDE;
    int cnt = min(bcur[b], BSTRIDE);
    int end = start + cnt;
    hist[t] = 0;
    hist[t + 256] = 0;
    __syncthreads();
    for (int i = start + t; i < end; i += 256)
        atomicAdd(&hist[recs[i] & 511], 1);
    __syncthreads();
    int h0 = hist[2 * t], h1 = hist[2 * t + 1];
    int e0 = scan256(h0 + h1, wsum);
    excl[2 * t] = e0;
    excl[2 * t + 1] = e0 + h0;
    int n0 = nbase + 2 * t, n1 = nbase + 2 * t + 1;
    if (n0 < N) {
        rowse[n0] = make_int2(start + e0, start + e0 + h0);
        dis[n0] = rsqrtf((float)(h0 + 1));
    }
    if (n1 < N) {
        rowse[n1] = make_int2(start + e0 + h0, start + e0 + h0 + h1);
        dis[n1] = rsqrtf((float)(h1 + 1));
    }
    __syncthreads();
    if (cnt <= CAP) {
        for (int i = start + t; i < end; i += 256) {
            int r = recs[i];
            int p = atomicAdd(&excl[r & 511], 1);
            srcsL[p] = ((unsigned)r) >> SHIFT;
        }
        __syncthreads();
        for (int i = t; i < cnt; i += 256) srcs[start + i] = srcsL[i];
    } else {  // pathological bucket: direct scatter (correct, slow)
        for (int i = start + t; i < end; i += 256) {
            int r = recs[i];
            int p = atomicAdd(&excl[r & 511], 1);
            srcs[start + p] = ((unsigned)r) >> SHIFT;
        }
    }
}

// Y = X @ W -> f16 panel-major, via MFMA 16x16x32.
// L2=false (layer1): X f32 row-major [M,128]; out panel16: Y[t][M][16],
//   col c=t*16+m16 -> panel t slot m16.
// L2=true (layer2): X f16 panel16 [8][M][16] (A[c] = 16B at panel
//   2c+(quad>>1), off (quad&1)*8); out mu/lv-interleaved panels: col c<64
//   (mu c) -> panel c>>3 slot c&7; c>=64 (lv c-64) -> panel (c-64)>>3 slot
//   8+((c-64)&7).
// W cols [0,split) from Wa (f32, row stride split), [split,128) from Wb.
// If zcur != nullptr, block 0 zeroes zcur[0..nz) (replaces a memset launch).
// Verified layouts (learn_hip m89/m120):
//   A[m=lane&15][k=quad*8+j], B[k=quad*8+j][n=lane&15],
//   C/D col=lane&15 row=quad*4+reg.
template <bool L2>
__global__ __launch_bounds__(256) void k_gemm(const void* __restrict__ Xv,
                                              const float* __restrict__ Wa,
                                              const float* __restrict__ Wb,
                                              int split,
                                              _Float16* __restrict__ Y,
                                              int M, int ngroups,
                                              int* __restrict__ zcur, int nz) {
    __shared__ _Float16 Wl[16384];  // 32 KB swizzled
    int tid = threadIdx.x;
    if (zcur && blockIdx.x == 0 && tid < nz) zcur[tid] = 0;
    int wbs = 128 - split;
    for (int i = tid; i < 16384; i += 256) {
        int k = i >> 7, n = i & 127;
        float v = (n < split) ? Wa[k * split + n] : Wb[k * wbs + (n - split)];
        int tt = n >> 4, c = (k >> 5), q = (k >> 3) & 3, ln = q * 16 + (n & 15);
        Wl[(((tt * 4 + c) * 64) + ln) * 8 + (k & 7)] = (_Float16)v;
    }
    __syncthreads();

    int lane = tid & 63, w = tid >> 6;
    f16x8 B[32];
#pragma unroll
    for (int i = 0; i < 32; i++)
        B[i] = *(const f16x8*)&Wl[(i * 64 + lane) * 8];

    int m16 = lane & 15, quad = lane >> 4;
    int M16 = M * 16;
    for (int g = blockIdx.x; g < ngroups; g += gridDim.x) {
        int rowbase = g * 64 + w * 16;
        if (rowbase >= M) continue;
        int arow = min(rowbase + m16, M - 1);
        f16x8 A[4];
        if (L2) {
            const _Float16* X = (const _Float16*)Xv;
#pragma unroll
            for (int c = 0; c < 4; c++) {
                int pa = 2 * c + (quad >> 1);
                A[c] = *(const f16x8*)&X[pa * M16 + arow * 16 + (quad & 1) * 8];
            }
        } else {
            const float* X = (const float*)Xv;
#pragma unroll
            for (int c = 0; c < 4; c++) {
                float4 u0 = *(const float4*)&X[arow * 128 + c * 32 + quad * 8];
                float4 u1 = *(const float4*)&X[arow * 128 + c * 32 + quad * 8 + 4];
                f16x8 a;
                a[0] = (_Float16)u0.x; a[1] = (_Float16)u0.y;
                a[2] = (_Float16)u0.z; a[3] = (_Float16)u0.w;
                a[4] = (_Float16)u1.x; a[5] = (_Float16)u1.y;
                a[6] = (_Float16)u1.z; a[7] = (_Float16)u1.w;
                A[c] = a;
            }
        }

        f32x4 acc[8];
#pragma unroll
        for (int t = 0; t < 8; t++) acc[t] = (f32x4)(0.f);
#pragma unroll
        for (int t = 0; t < 8; t++)
#pragma unroll
            for (int c = 0; c < 4; c++)
                acc[t] = __builtin_amdgcn_mfma_f32_16x16x32_f16(
                    A[c], B[t * 4 + c], acc[t], 0, 0, 0);

#pragma unroll
        for (int r = 0; r < 4; r++) {
            int row = rowbase + quad * 4 + r;
            if (row < M) {
#pragma unroll
                for (int t = 0; t < 8; t++) {
                    if (!L2) {
                        Y[t * M16 + row * 16 + m16] = (_Float16)acc[t][r];
                    } else {
                        int p = (t < 4) ? (2 * t + (m16 >> 3))
                                        : (2 * (t - 4) + (m16 >> 3));
                        int slot = ((t < 4) ? 0 : 8) + (m16 & 7);
                        Y[p * M16 + row * 16 + slot] = (_Float16)acc[t][r];
                    }
                }
            }
        }
    }
}

// Feature-panel aggregation. F is UNSCALED f16 panel-major [8][N][16].
// Block processes panel p = blockIdx%8 only (XCD-affine via round-robin
// dispatch -> per-XCD gather working set = 3.2MB, L2-resident).
// Per wave: WNODES nodes; per trip 16 edges x 4 lanes x f16x4 (8B).
// srcs via NT loads (streamed 8x, don't pollute L2). Butterfly over edge
// bits (masks 4,8,16,32); lanes 0-3 hold the 4 slot-quads.
// OF16 (agg1): panel16 cols p*16+slot; h = relu(di*S + b1) -> f16x4.
// else (agg2): interleaved panels (slots 0-7 mu cols p*8.., 8-15 lv same);
//   mu/lv f32x4 NT stores + fused z (lv pulled via shfl_xor 2).
template <bool OF16>
__global__ __launch_bounds__(256) void k_agg(const _Float16* __restrict__ F,
                                             const float* __restrict__ dis,
                                             const int2* __restrict__ rowse,
                                             const int* __restrict__ srcs,
                                             const float* __restrict__ ba,
                                             const float* __restrict__ bb,
                                             void* __restrict__ outA,
                                             void* __restrict__ outB,
                                             const float* __restrict__ eps,
                                             float* __restrict__ z, int N) {
    int p = blockIdx.x & 7;
    int chunk = blockIdx.x >> 3;
    int wid = threadIdx.x >> 6, lane = threadIdx.x & 63;
    int esub = lane >> 2, sq = lane & 3;
    int N16 = N * 16;
    const _Float16* Fp = F + p * N16;

    int nodebase = (chunk * 4 + wid) * WNODES;
    for (int ni = 0; ni < WNODES; ni++) {
        int node = nodebase + ni;
        if (node >= N) return;          // wave-uniform
        int2 se = rowse[node];
        float di = dis[node];
        float a0 = 0.f, a1 = 0.f, a2 = 0.f, a3 = 0.f;
        for (int t = se.x; t < se.y; t += 16) {
            int eidx = t + esub;
            bool ok = eidx < se.y;
            int src = ok ? __builtin_nontemporal_load(&srcs[eidx]) : 0;
            float d = ok ? dis[src] : 0.f;
            f16x4 v = *(const f16x4*)&Fp[src * 16 + sq * 4];
            a0 = fmaf(d, (float)v[0], a0);
            a1 = fmaf(d, (float)v[1], a1);
            a2 = fmaf(d, (float)v[2], a2);
            a3 = fmaf(d, (float)v[3], a3);
        }
#pragma unroll
        for (int m = 4; m <= 32; m <<= 1) {
            a0 += __shfl_xor(a0, m);
            a1 += __shfl_xor(a1, m);
            a2 += __shfl_xor(a2, m);
            a3 += __shfl_xor(a3, m);
        }
        // self term (weight di), replicated on all lanes
        f16x4 vs = *(const f16x4*)&Fp[node * 16 + sq * 4];
        a0 = fmaf(di, (float)vs[0], a0);
        a1 = fmaf(di, (float)vs[1], a1);
        a2 = fmaf(di, (float)vs[2], a2);
        a3 = fmaf(di, (float)vs[3], a3);

        if constexpr (OF16) {
            if (lane < 4) {
                float4 b = *(const float4*)&ba[p * 16 + sq * 4];
                f16x4 o;
                o[0] = (_Float16)fmaxf(fmaf(di, a0, b.x), 0.f);
                o[1] = (_Float16)fmaxf(fmaf(di, a1, b.y), 0.f);
                o[2] = (_Float16)fmaxf(fmaf(di, a2, b.z), 0.f);
                o[3] = (_Float16)fmaxf(fmaf(di, a3, b.w), 0.f);
                *(f16x4*)&((_Float16*)outA)[p * N16 + node * 16 + sq * 4] = o;
            }
        } else {
            bool isMu = sq < 2;
            int cb = p * 8 + (sq & 1) * 4;   // column base within [0,64)
            const float* bp = isMu ? ba : bb;
            float4 b = *(const float4*)&bp[cb];
            float o0 = fmaf(di, a0, b.x);
            float o1 = fmaf(di, a1, b.y);
            float o2 = fmaf(di, a2, b.z);
            float o3 = fmaf(di, a3, b.w);
            if (lane < 4) {
                float* op = isMu ? (float*)outA : (float*)outB;
                f32x4 s;
                s[0] = o0; s[1] = o1; s[2] = o2; s[3] = o3;
                __builtin_nontemporal_store(s, (f32x4*)&op[node * 64 + cb]);
            }
            // z: lanes 0,1 (mu) pull lv of same cols from lanes 2,3
            float l0 = __shfl_xor(o0, 2);
            float l1 = __shfl_xor(o1, 2);
            float l2 = __shfl_xor(o2, 2);
            float l3 = __shfl_xor(o3, 2);
            if (lane < 2) {
                float4 e = *(const float4*)&eps[node * 64 + cb];
                f32x4 zv;
                zv[0] = fmaf(e.x, expf(0.5f * l0), o0);
                zv[1] = fmaf(e.y, expf(0.5f * l1), o1);
                zv[2] = fmaf(e.z, expf(0.5f * l2), o2);
                zv[3] = fmaf(e.w, expf(0.5f * l3), o3);
                __builtin_nontemporal_store(zv, (f32x4*)&z[node * 64 + cb]);
            }
        }
    }
}

extern "C" void kernel_launch(void* const* d_in, const int* in_sizes, int n_in,
                              void* d_out, int out_size, void* d_ws, size_t ws_size,
                              hipStream_t stream) {
    const float* x   = (const float*)d_in[0];
    const int*   ei  = (const int*)d_in[1];
    const float* W1  = (const float*)d_in[2];
    const float* b1  = (const float*)d_in[3];
    const float* Wmu = (const float*)d_in[4];
    const float* bmu = (const float*)d_in[5];
    const float* Wlv = (const float*)d_in[6];
    const float* blv = (const float*)d_in[7];
    const float* eps = (const float*)d_in[8];

    int N = in_sizes[0] / 128;   // 100000
    int E = in_sizes[1] / 2;     // 1600000
    const int* rowi = ei;        // edge_index[0]
    const int* coli = ei + E;    // edge_index[1]
    int NB = (N + (1 << SHIFT) - 1) >> SHIFT;   // 196 buckets

    char* ws = (char*)d_ws;
    size_t off = 0;
    auto alloc = [&](size_t bytes) -> void* {
        void* p = ws + off;
        off += (bytes + 255) & ~(size_t)255;
        return p;
    };
    _Float16* bufA = (_Float16*)alloc((size_t)N * 128 * 2);  // F1, F2 (panel)
    _Float16* bufB = (_Float16*)alloc((size_t)N * 128 * 2);  // h (panel16)
    float* dis    = (float*)alloc((size_t)N * 4);
    int2*  rowse  = (int2*)alloc((size_t)N * 8);
    int*   srcs   = (int*)alloc((size_t)NB * BSTRIDE * 4);
    int*   recs   = (int*)alloc((size_t)NB * BSTRIDE * 4);  // packed row<<9|col
    int*   bcur   = (int*)alloc((size_t)NB * 4);

    float* zo  = (float*)d_out;                 // [N,64]
    float* muo = zo + (size_t)N * 64;           // [N,64]
    float* lvo = zo + (size_t)N * 128;          // [N,64]

    int ngroups = (N + 63) / 64;
    int gblk = ngroups < 640 ? ngroups : 640;
    int aggblk = ((N + 127) / 128) * 8;   // chunks x 8 panels
    // F1 = x @ W1 (f16 panel16, MFMA); also zeroes bcur for the CSR build.
    k_gemm<false><<<gblk, 256, 0, stream>>>(x, W1, W1, 128, bufA, N, ngroups,
                                            bcur, NB);
    k_bucket<<<(E + EPB - 1) / EPB, 256, 0, stream>>>(rowi, coli, bcur, recs,
                                                      E, NB);
    k_fill2<<<NB, 256, 0, stream>>>(recs, bcur, rowse, dis, srcs, N);
    // h = relu(dis-weighted agg of F1 + b1)   (f16 panel16)
    k_agg<true><<<aggblk, 256, 0, stream>>>(bufA, dis, rowse, srcs,
                                            b1, b1, bufB, bufB,
                                            nullptr, nullptr, N);
    // F2 = h @ [Wmu|Wlv]   (f16 interleaved panels, MFMA)
    k_gemm<true><<<gblk, 256, 0, stream>>>(bufB, Wmu, Wlv, 64, bufA, N, ngroups,
                                           nullptr, 0);
    // mu/lv = dis-weighted agg + b ; z fused in-wave
    k_agg<false><<<aggblk, 256, 0, stream>>>(bufA, dis, rowse, srcs,
                                             bmu, blv, muo, lvo,
                                             eps, zo, N);
}

// Round 8
// 543.129 us; speedup vs baseline: 1.8641x; 1.8641x over previous
//
#include <hip/hip_runtime.h>
#include <math.h>

// VGAE forward: 3x GCNConv + reparameterize.
// Pipeline (5 dispatches): memset(bar) -> k_build (GEMM1 + zero bcur |
//   gridbar | bucket-sort | gridbar | fill2) -> agg1(+b1,relu,f16) ->
//   MFMA GEMM2 (W_mu|W_lv fused) -> agg2 (f32 mu/lv + fused z).
// R6: k_agg 16B-lane gather; z fused into agg2.
// R7/R10 (REVERTED): dest-side seg-blocking AND feature-panel partitioning
//   both failed to cut agg L2-miss traffic (FETCH pinned ~207MB) and both
//   destroyed gather MLP. Agg structure CLOSED at the R9 form (~3.3TB/s).
// R9: fixed-stride buckets, per-edge dis, GEMM1 zeroes bcur. 381us verified.
// R11 (coop, container-failed): hipLaunchCooperativeKernel under graph
//   capture is the suspect. R12: SAME fusion, capture-safe — software
//   sense-reversal grid barrier (device atomics + s_sleep spin; gen read
//   precedes own arrival-add so release can't race it; 8B memset/launch
//   resets state). Co-residency by construction: 512 blocks,
//   launch_bounds(256,2), 53.3KB LDS x2 = 106.6 <= 160KB -> 2 blk/CU x 256.

#define SHIFT 9            // nodes per bucket = 512
#define EPB 2048           // edges per bucket-phase chunk
#define BSTRIDE 12288      // recs/srcs slots per bucket (1.5x Poisson mean)
#define NBLD 512           // k_build blocks (co-resident at 2/CU)

using f32x4 = __attribute__((ext_vector_type(4))) float;
using f16x8 = __attribute__((ext_vector_type(8))) _Float16;

// Block-wide (256 thr) exclusive scan of one int per thread.
__device__ inline int scan256(int v, int* wsum) {
    __syncthreads();  // protect wsum reuse across calls
    int lane = threadIdx.x & 63, wid = threadIdx.x >> 6;
    int s = v;
#pragma unroll
    for (int d = 1; d < 64; d <<= 1) {
        int u = __shfl_up(s, d, 64);
        if (lane >= d) s += u;
    }
    if (lane == 63) wsum[wid] = s;
    __syncthreads();
    int off = 0;
    for (int w = 0; w < wid; w++) off += wsum[w];
    return off + s - v;
}

// Software grid barrier (sense-reversal, graph-capture-safe).
// bar[0]=arrival counter, bar[1]=generation flag. Both zeroed per launch by
// an 8B memset. gen is read BEFORE this block's arrival-add; release needs
// ALL arrivals, so it cannot precede any block's gen read. Last arriver
// resets the counter before bumping gen (spinners watch gen, not counter).
__device__ inline void gridbar(int* bar, int nblk) {
    __syncthreads();
    if (threadIdx.x == 0) {
        __threadfence();
        int gen = __hip_atomic_load(&bar[1], __ATOMIC_ACQUIRE,
                                    __HIP_MEMORY_SCOPE_AGENT);
        int v = atomicAdd(&bar[0], 1);
        if (v == nblk - 1) {
            bar[0] = 0;
            __threadfence();
            atomicAdd(&bar[1], 1);
        } else {
            while (__hip_atomic_load(&bar[1], __ATOMIC_ACQUIRE,
                                     __HIP_MEMORY_SCOPE_AGENT) == gen)
                __builtin_amdgcn_s_sleep(8);
        }
    }
    __syncthreads();
}

// Fused front-end: phase A = GEMM1 (Y = x @ W1 -> f16 [M,128]) and block 0
// zeroes bcur; gridbar; phase B = bucket-sort edges into fixed-stride
// per-bucket runs of packed (row<<9)|(col&511); gridbar; phase C =
// per-bucket histogram -> rowse/dis + sorted srcs burst.
// LDS: one 53.3KB union reused per phase -> 2 blocks/CU, 512 co-resident.
__global__ __launch_bounds__(256, 2) void k_build(
        const float* __restrict__ x, const float* __restrict__ W1,
        _Float16* __restrict__ Y, int M, int ngroups,
        const int* __restrict__ rowi, const int* __restrict__ coli,
        int* __restrict__ bcur, int* __restrict__ recs, int E, int nchunks,
        int2* __restrict__ rowse, float* __restrict__ dis,
        int* __restrict__ srcs, int NB, int* __restrict__ bar) {
    __shared__ __align__(16) char smem[53264];
    int t = threadIdx.x, w = t >> 6;

    // ---------------- phase A: GEMM1 + zero bcur ----------------
    if (blockIdx.x == 0 && t < NB) bcur[t] = 0;
    {
        _Float16* Wl = (_Float16*)smem;  // 32KB swizzled B-frags
        for (int i = t; i < 16384; i += 256) {
            int k = i >> 7, n = i & 127;
            float v = W1[k * 128 + n];
            int tt = n >> 4, c = (k >> 5), q = (k >> 3) & 3,
                ln = q * 16 + (n & 15);
            Wl[(((tt * 4 + c) * 64) + ln) * 8 + (k & 7)] = (_Float16)v;
        }
        __syncthreads();
        int lane = t & 63;
        f16x8 B[32];
#pragma unroll
        for (int i = 0; i < 32; i++)
            B[i] = *(const f16x8*)&Wl[(i * 64 + lane) * 8];
        int m16 = lane & 15, quad = lane >> 4;
        for (int g = blockIdx.x; g < ngroups; g += gridDim.x) {
            int rowbase = g * 64 + w * 16;
            if (rowbase >= M) continue;
            int arow = min(rowbase + m16, M - 1);
            f16x8 A[4];
#pragma unroll
            for (int c = 0; c < 4; c++) {
                float4 u0 = *(const float4*)&x[arow * 128 + c * 32 + quad * 8];
                float4 u1 = *(const float4*)&x[arow * 128 + c * 32 + quad * 8 + 4];
                f16x8 a;
                a[0] = (_Float16)u0.x; a[1] = (_Float16)u0.y;
                a[2] = (_Float16)u0.z; a[3] = (_Float16)u0.w;
                a[4] = (_Float16)u1.x; a[5] = (_Float16)u1.y;
                a[6] = (_Float16)u1.z; a[7] = (_Float16)u1.w;
                A[c] = a;
            }
            f32x4 acc[8];
#pragma unroll
            for (int tt = 0; tt < 8; tt++) acc[tt] = (f32x4)(0.f);
#pragma unroll
            for (int tt = 0; tt < 8; tt++)
#pragma unroll
                for (int c = 0; c < 4; c++)
                    acc[tt] = __builtin_amdgcn_mfma_f32_16x16x32_f16(
                        A[c], B[tt * 4 + c], acc[tt], 0, 0, 0);
#pragma unroll
            for (int r = 0; r < 4; r++) {
                int row = rowbase + quad * 4 + r;
                if (row < M) {
#pragma unroll
                    for (int tt = 0; tt < 8; tt++)
                        Y[row * 128 + tt * 16 + m16] = (_Float16)acc[tt][r];
                }
            }
        }
    }
    gridbar(bar, NBLD);

    // ---------------- phase B: bucket-sort edges ----------------
    {
        int* lh    = (int*)smem;           // [4][256]
        int* lcur  = lh + 1024;            // [4][256]
        int* bexcl = lcur + 1024;          // [256]
        int* gbase = bexcl + 256;          // [256]
        int* bwsum = gbase + 256;          // [4]
        int2* stage = (int2*)(bwsum + 4);  // [2048]
        for (int chunk = blockIdx.x; chunk < nchunks; chunk += gridDim.x) {
            __syncthreads();
            lh[t] = 0; lh[256 + t] = 0; lh[512 + t] = 0; lh[768 + t] = 0;
            __syncthreads();
            int base = chunk * EPB;
            int nE = min(EPB, E - base);
            for (int i = t; i < nE; i += 256)
                atomicAdd(&lh[w * 256 + (coli[base + i] >> SHIFT)], 1);
            __syncthreads();
            int h0 = lh[t], h1 = lh[256 + t], h2 = lh[512 + t], h3 = lh[768 + t];
            int tot = h0 + h1 + h2 + h3;
            int ex = scan256(tot, bwsum);
            bexcl[t] = ex;
            lcur[t] = ex;
            lcur[256 + t] = ex + h0;
            lcur[512 + t] = ex + h0 + h1;
            lcur[768 + t] = ex + h0 + h1 + h2;
            if (t < NB && tot)
                gbase[t] = t * BSTRIDE + atomicAdd(&bcur[t], tot);
            __syncthreads();
            for (int i = t; i < nE; i += 256) {
                int r = rowi[base + i], c = coli[base + i];
                int p = atomicAdd(&lcur[w * 256 + (c >> SHIFT)], 1);
                stage[p] = make_int2(r, c);
            }
            __syncthreads();
            for (int i = t; i < nE; i += 256) {
                int2 r = stage[i];
                int bb = r.y >> SHIFT;
                int idx = gbase[bb] + (i - bexcl[bb]);
                if (idx - bb * BSTRIDE < BSTRIDE)  // statistically never false
                    recs[idx] = (r.x << SHIFT) | (r.y & 511);
            }
        }
    }
    gridbar(bar, NBLD);

    // ---------------- phase C: per-bucket fill ----------------
    {
        int* hist  = (int*)smem;           // [512]
        int* fexcl = hist + 512;           // [512]
        int* fwsum = fexcl + 512;          // [4]
        int* srcsL = fwsum + 4;            // [BSTRIDE]
        for (int b = blockIdx.x; b < NB; b += gridDim.x) {
            __syncthreads();
            int nbase = b << SHIFT;
            int start = b * BSTRIDE;
            int cnt = min(bcur[b], BSTRIDE);
            int end = start + cnt;
            hist[t] = 0;
            hist[t + 256] = 0;
            __syncthreads();
            for (int i = start + t; i < end; i += 256)
                atomicAdd(&hist[recs[i] & 511], 1);
            __syncthreads();
            int h0 = hist[2 * t], h1 = hist[2 * t + 1];
            int e0 = scan256(h0 + h1, fwsum);
            fexcl[2 * t] = e0;
            fexcl[2 * t + 1] = e0 + h0;
            int n0 = nbase + 2 * t, n1 = nbase + 2 * t + 1;
            if (n0 < M) {
                rowse[n0] = make_int2(start + e0, start + e0 + h0);
                dis[n0] = rsqrtf((float)(h0 + 1));
            }
            if (n1 < M) {
                rowse[n1] = make_int2(start + e0 + h0, start + e0 + h0 + h1);
                dis[n1] = rsqrtf((float)(h1 + 1));
            }
            __syncthreads();
            for (int i = start + t; i < end; i += 256) {
                int r = recs[i];
                int p = atomicAdd(&fexcl[r & 511], 1);
                srcsL[p] = ((unsigned)r) >> SHIFT;
            }
            __syncthreads();
            for (int i = t; i < cnt; i += 256) srcs[start + i] = srcsL[i];
        }
    }
}

// Y[M,128] = X[M,128] @ [Wa|Wb] -> f16 (X f16 row-major), via MFMA 16x16x32.
// W cols [0,split) from Wa (f32, row stride split), [split,128) from Wb.
// Verified layouts (learn_hip m89/m120):
//   A[m=lane&15][k=quad*8+j], B[k=quad*8+j][n=lane&15],
//   C/D col=lane&15 row=quad*4+reg.
__global__ __launch_bounds__(256) void k_gemm2(const _Float16* __restrict__ X,
                                               const float* __restrict__ Wa,
                                               const float* __restrict__ Wb,
                                               int split,
                                               _Float16* __restrict__ Y,
                                               int M, int ngroups) {
    __shared__ _Float16 Wl[16384];  // 32 KB swizzled
    int tid = threadIdx.x;
    int wbs = 128 - split;
    for (int i = tid; i < 16384; i += 256) {
        int k = i >> 7, n = i & 127;
        float v = (n < split) ? Wa[k * split + n] : Wb[k * wbs + (n - split)];
        int tt = n >> 4, c = (k >> 5), q = (k >> 3) & 3, ln = q * 16 + (n & 15);
        Wl[(((tt * 4 + c) * 64) + ln) * 8 + (k & 7)] = (_Float16)v;
    }
    __syncthreads();

    int lane = tid & 63, w = tid >> 6;
    f16x8 B[32];
#pragma unroll
    for (int i = 0; i < 32; i++)
        B[i] = *(const f16x8*)&Wl[(i * 64 + lane) * 8];

    int m16 = lane & 15, quad = lane >> 4;
    for (int g = blockIdx.x; g < ngroups; g += gridDim.x) {
        int rowbase = g * 64 + w * 16;
        if (rowbase >= M) continue;
        int arow = min(rowbase + m16, M - 1);
        f16x8 A[4];
#pragma unroll
        for (int c = 0; c < 4; c++)
            A[c] = *(const f16x8*)&X[arow * 128 + c * 32 + quad * 8];

        f32x4 acc[8];
#pragma unroll
        for (int t = 0; t < 8; t++) acc[t] = (f32x4)(0.f);
#pragma unroll
        for (int t = 0; t < 8; t++)
#pragma unroll
            for (int c = 0; c < 4; c++)
                acc[t] = __builtin_amdgcn_mfma_f32_16x16x32_f16(
                    A[c], B[t * 4 + c], acc[t], 0, 0, 0);

#pragma unroll
        for (int r = 0; r < 4; r++) {
            int row = rowbase + quad * 4 + r;
            if (row < M) {
#pragma unroll
                for (int t = 0; t < 8; t++)
                    Y[row * 128 + t * 16 + m16] = (_Float16)acc[t][r];
            }
        }
    }
}

// F is UNSCALED f16 [N,128]. out[i] = b + dis_i*(dis_i*F[i] + sum dis_s*F[s]).
// One wave per node; 16 lanes x f16x8 (16B) cover a row; the wave's 4
// lane-groups process 4 edges per trip (1KB/VMEM), main loop 16 edges deep.
// dis[src] applied per-edge (fma; dis is L2-resident). Butterfly (16,32).
// OF16: output f16 [N,128] with relu (layer 1).
// else: mu->outA, lv->outB (f32 [N,64]) + fused z = mu+eps*exp(.5*lv).
template <bool OF16>
__global__ __launch_bounds__(256) void k_agg(const _Float16* __restrict__ F,
                                             const float* __restrict__ dis,
                                             const int2* __restrict__ rowse,
                                             const int* __restrict__ srcs,
                                             const float* __restrict__ ba,
                                             const float* __restrict__ bb,
                                             void* __restrict__ outA,
                                             void* __restrict__ outB,
                                             const float* __restrict__ eps,
                                             float* __restrict__ z, int N) {
    int node = blockIdx.x * 4 + (threadIdx.x >> 6);
    if (node >= N) return;
    int lane = threadIdx.x & 63;
    int g = lane >> 4, sl = lane & 15;
    const f16x8* Fr = (const f16x8*)F;   // row r chunk c at Fr[r*16 + c]

    float di = dis[node];
    float acc[8];
#pragma unroll
    for (int j = 0; j < 8; j++) acc[j] = 0.f;
    if (g == 0) {  // self term: dis_i * F[i]
        f16x8 v = Fr[node * 16 + sl];
#pragma unroll
        for (int j = 0; j < 8; j++) acc[j] = di * (float)v[j];
    }

    int2 se = rowse[node];
    int s = se.x, e = se.y;
    int t = s;
    for (; t + 16 <= e; t += 16) {
        int i0 = srcs[t + g];
        int i1 = srcs[t + 4 + g];
        int i2 = srcs[t + 8 + g];
        int i3 = srcs[t + 12 + g];
        float d0 = dis[i0], d1 = dis[i1], d2 = dis[i2], d3 = dis[i3];
        f16x8 v0 = Fr[i0 * 16 + sl];
        f16x8 v1 = Fr[i1 * 16 + sl];
        f16x8 v2 = Fr[i2 * 16 + sl];
        f16x8 v3 = Fr[i3 * 16 + sl];
#pragma unroll
        for (int j = 0; j < 8; j++)
            acc[j] = fmaf(d0, (float)v0[j],
                     fmaf(d1, (float)v1[j],
                     fmaf(d2, (float)v2[j],
                     fmaf(d3, (float)v3[j], acc[j]))));
    }
    if (t + 8 <= e) {
        int i0 = srcs[t + g];
        int i1 = srcs[t + 4 + g];
        float d0 = dis[i0], d1 = dis[i1];
        f16x8 v0 = Fr[i0 * 16 + sl];
        f16x8 v1 = Fr[i1 * 16 + sl];
#pragma unroll
        for (int j = 0; j < 8; j++)
            acc[j] = fmaf(d0, (float)v0[j], fmaf(d1, (float)v1[j], acc[j]));
        t += 8;
    }
    if (t + 4 <= e) {
        int i0 = srcs[t + g];
        float d0 = dis[i0];
        f16x8 v0 = Fr[i0 * 16 + sl];
#pragma unroll
        for (int j = 0; j < 8; j++) acc[j] = fmaf(d0, (float)v0[j], acc[j]);
        t += 4;
    }
    if (t < e) {  // masked tail: 1..3 edges
        int idx = t + g;
        bool ok = idx < e;
        int i0 = ok ? srcs[idx] : 0;
        float d0 = dis[i0];
        f16x8 v0 = Fr[i0 * 16 + sl];
        if (ok) {
#pragma unroll
            for (int j = 0; j < 8; j++) acc[j] = fmaf(d0, (float)v0[j], acc[j]);
        }
    }

    // butterfly reduce over the 4 lane-groups (all lanes end with full sum)
#pragma unroll
    for (int j = 0; j < 8; j++) {
        acc[j] += __shfl_xor(acc[j], 16);
        acc[j] += __shfl_xor(acc[j], 32);
    }

    if constexpr (OF16) {
        float4 b0 = *(const float4*)&ba[sl * 8];
        float4 b1 = *(const float4*)&ba[sl * 8 + 4];
        if (lane < 16) {
            f16x8 o;
            o[0] = (_Float16)fmaxf(fmaf(di, acc[0], b0.x), 0.f);
            o[1] = (_Float16)fmaxf(fmaf(di, acc[1], b0.y), 0.f);
            o[2] = (_Float16)fmaxf(fmaf(di, acc[2], b0.z), 0.f);
            o[3] = (_Float16)fmaxf(fmaf(di, acc[3], b0.w), 0.f);
            o[4] = (_Float16)fmaxf(fmaf(di, acc[4], b1.x), 0.f);
            o[5] = (_Float16)fmaxf(fmaf(di, acc[5], b1.y), 0.f);
            o[6] = (_Float16)fmaxf(fmaf(di, acc[6], b1.z), 0.f);
            o[7] = (_Float16)fmaxf(fmaf(di, acc[7], b1.w), 0.f);
            ((f16x8*)outA)[node * 16 + sl] = o;
        }
    } else {
        // lanes (sl<8): mu cols sl*8..+7 ; lanes (sl>=8): lv cols (sl-8)*8..+7
        const float* bp = (sl < 8) ? ba : bb;
        int cb = (sl & 7) * 8;
        float4 b0 = *(const float4*)&bp[cb];
        float4 b1 = *(const float4*)&bp[cb + 4];
        float o[8];
        o[0] = fmaf(di, acc[0], b0.x);
        o[1] = fmaf(di, acc[1], b0.y);
        o[2] = fmaf(di, acc[2], b0.z);
        o[3] = fmaf(di, acc[3], b0.w);
        o[4] = fmaf(di, acc[4], b1.x);
        o[5] = fmaf(di, acc[5], b1.y);
        o[6] = fmaf(di, acc[6], b1.z);
        o[7] = fmaf(di, acc[7], b1.w);
        if (lane < 16) {
            float* op = (sl < 8) ? (float*)outA : (float*)outB;
            f32x4 s0, s1;
            s0[0] = o[0]; s0[1] = o[1]; s0[2] = o[2]; s0[3] = o[3];
            s1[0] = o[4]; s1[1] = o[5]; s1[2] = o[6]; s1[3] = o[7];
            __builtin_nontemporal_store(s0, (f32x4*)&op[node * 64 + cb]);
            __builtin_nontemporal_store(s1, (f32x4*)&op[node * 64 + cb + 4]);
        }
        // fused reparameterize: lane l (<8) pulls lv chunk from lane l+8
        float lvv[8];
#pragma unroll
        for (int j = 0; j < 8; j++) lvv[j] = __shfl_xor(o[j], 8);
        if (lane < 8) {
            int zb = node * 64 + sl * 8;
            float4 e0 = *(const float4*)&eps[zb];
            float4 e1 = *(const float4*)&eps[zb + 4];
            f32x4 z0, z1;
            z0[0] = fmaf(e0.x, expf(0.5f * lvv[0]), o[0]);
            z0[1] = fmaf(e0.y, expf(0.5f * lvv[1]), o[1]);
            z0[2] = fmaf(e0.z, expf(0.5f * lvv[2]), o[2]);
            z0[3] = fmaf(e0.w, expf(0.5f * lvv[3]), o[3]);
            z1[0] = fmaf(e1.x, expf(0.5f * lvv[4]), o[4]);
            z1[1] = fmaf(e1.y, expf(0.5f * lvv[5]), o[5]);
            z1[2] = fmaf(e1.z, expf(0.5f * lvv[6]), o[6]);
            z1[3] = fmaf(e1.w, expf(0.5f * lvv[7]), o[7]);
            __builtin_nontemporal_store(z0, (f32x4*)&z[zb]);
            __builtin_nontemporal_store(z1, (f32x4*)&z[zb + 4]);
        }
    }
}

extern "C" void kernel_launch(void* const* d_in, const int* in_sizes, int n_in,
                              void* d_out, int out_size, void* d_ws, size_t ws_size,
                              hipStream_t stream) {
    const float* x   = (const float*)d_in[0];
    const int*   ei  = (const int*)d_in[1];
    const float* W1  = (const float*)d_in[2];
    const float* b1  = (const float*)d_in[3];
    const float* Wmu = (const float*)d_in[4];
    const float* bmu = (const float*)d_in[5];
    const float* Wlv = (const float*)d_in[6];
    const float* blv = (const float*)d_in[7];
    const float* eps = (const float*)d_in[8];

    int N = in_sizes[0] / 128;   // 100000
    int E = in_sizes[1] / 2;     // 1600000
    const int* rowi = ei;        // edge_index[0]
    const int* coli = ei + E;    // edge_index[1]
    int NB = (N + (1 << SHIFT) - 1) >> SHIFT;   // 196 buckets
    int nchunks = (E + EPB - 1) / EPB;

    char* ws = (char*)d_ws;
    size_t off = 0;
    auto alloc = [&](size_t bytes) -> void* {
        void* p = ws + off;
        off += (bytes + 255) & ~(size_t)255;
        return p;
    };
    _Float16* bufA = (_Float16*)alloc((size_t)N * 128 * 2);  // F1, F2
    _Float16* bufB = (_Float16*)alloc((size_t)N * 128 * 2);  // h (f16)
    float* dis    = (float*)alloc((size_t)N * 4);
    int2*  rowse  = (int2*)alloc((size_t)N * 8);
    int*   srcs   = (int*)alloc((size_t)NB * BSTRIDE * 4);
    int*   recs   = (int*)alloc((size_t)NB * BSTRIDE * 4);  // packed row<<9|col
    int*   bcur   = (int*)alloc((size_t)NB * 4);
    int*   bar    = (int*)alloc(8);                          // grid barrier

    float* zo  = (float*)d_out;                 // [N,64]
    float* muo = zo + (size_t)N * 64;           // [N,64]
    float* lvo = zo + (size_t)N * 128;          // [N,64]

    int ngroups = (N + 63) / 64;

    hipMemsetAsync(bar, 0, 8, stream);
    // fused front-end: GEMM1 + CSR build in one dispatch (software gridbar)
    k_build<<<NBLD, 256, 0, stream>>>(x, W1, bufA, N, ngroups, rowi, coli,
                                      bcur, recs, E, nchunks, rowse, dis,
                                      srcs, NB, bar);
    // h = relu(dis_i*(dis_i*F1[i] + sum dis_s*F1[s]) + b1)   (f16)
    k_agg<true><<<(N + 3) / 4, 256, 0, stream>>>(bufA, dis, rowse, srcs,
                                                 b1, b1, bufB, bufB,
                                                 nullptr, nullptr, N);
    // F2 = h @ [Wmu|Wlv]   (f16, MFMA)
    int gblk = ngroups < 640 ? ngroups : 640;
    k_gemm2<<<gblk, 256, 0, stream>>>(bufB, Wmu, Wlv, 64, bufA, N, ngroups);
    // mu/lv = dis-weighted agg + b ; z fused in-wave
    k_agg<false><<<(N + 3) / 4, 256, 0, stream>>>(bufA, dis, rowse, srcs,
                                                  bmu, blv, muo, lvo,
                                                  eps, zo, N);
}

// Round 10
// 393.540 us; speedup vs baseline: 2.5726x; 1.3801x over previous
//
#include <hip/hip_runtime.h>
#include <math.h>

// VGAE forward: 3x GCNConv + reparameterize.
// Pipeline (6 dispatches): MFMA GEMM1 (zeroes bcur) -> bucket-sort CSR build
//   (k_bucket fixed-stride + k_fill2) -> agg1(+b1,relu,f16) -> MFMA GEMM2
//   (W_mu|W_lv fused) -> agg2 (f32 mu/lv + fused z).
// R6: k_agg 16B-lane gather; z fused into agg2.
// R7/R10 (REVERTED): dest-side seg-blocking AND feature-panel partitioning
//   both failed to cut agg L2-miss traffic (FETCH pinned ~207MB = NXCD x |F|)
//   and destroyed gather MLP. Agg structure CLOSED at this form (~3.3TB/s
//   fabric rate on random 256B gathers; VALUBusy 55%, occ 74%).
// R9: fixed-stride buckets, per-edge dis, GEMM1 zeroes bcur. 381us verified.
// R11/R12 (REVERTED): front-end fusion failed both ways — cooperative launch
//   killed the container (graph-capture hostile); software grid barrier ran
//   at 2.6% VALUBusy / 23% occupancy = 256us vs ~40us of work. CLOSED.
// R13: R9 verbatim + nontemporal loads on the read-once srcs/rowse streams
//   (rowse via int* view — NT builtin rejects HIP_vector_type, cf. R2).

#define SHIFT 9            // nodes per bucket = 512
#define EPB 2048           // edges per k_bucket block
#define BSTRIDE 12288      // recs/srcs slots per bucket (1.5x Poisson mean)
#define CAP 15104          // fill2 LDS srcs capacity

using f32x4 = __attribute__((ext_vector_type(4))) float;
using f32x2 = __attribute__((ext_vector_type(2))) float;
using f16x8 = __attribute__((ext_vector_type(8))) _Float16;

// Block-wide (256 thr) exclusive scan of one int per thread.
__device__ inline int scan256(int v, int* wsum) {
    __syncthreads();  // protect wsum reuse across calls
    int lane = threadIdx.x & 63, wid = threadIdx.x >> 6;
    int s = v;
#pragma unroll
    for (int d = 1; d < 64; d <<= 1) {
        int u = __shfl_up(s, d, 64);
        if (lane >= d) s += u;
    }
    if (lane == 63) wsum[wid] = s;
    __syncthreads();
    int off = 0;
    for (int w = 0; w < wid; w++) off += wsum[w];
    return off + s - v;
}

// Bin EPB edges into LDS by bucket, burst-write packed (row<<9)|(col&511)
// records into the bucket's fixed-stride region (base = b*BSTRIDE + atomic
// cursor). Two passes over the (L2-hot) chunk; per-wave histograms+cursors.
__global__ __launch_bounds__(256) void k_bucket(const int* __restrict__ rowi,
                                                const int* __restrict__ coli,
                                                int* __restrict__ bcur,
                                                int* __restrict__ recs,
                                                int E, int NB) {
    __shared__ int lh[4][256], lcur[4][256], excl[256], gbase[256], wsum[4];
    __shared__ int2 stage[EPB];
    int t = threadIdx.x, w = t >> 6;
    lh[0][t] = 0; lh[1][t] = 0; lh[2][t] = 0; lh[3][t] = 0;
    __syncthreads();
    int base = blockIdx.x * EPB;
    int nE = min(EPB, E - base);
    // pass A: per-wave histogram
    for (int i = t; i < nE; i += 256)
        atomicAdd(&lh[w][coli[base + i] >> SHIFT], 1);
    __syncthreads();
    int h0 = lh[0][t], h1 = lh[1][t], h2 = lh[2][t], h3 = lh[3][t];
    int tot = h0 + h1 + h2 + h3;
    int ex = scan256(tot, wsum);
    excl[t] = ex;
    lcur[0][t] = ex;
    lcur[1][t] = ex + h0;
    lcur[2][t] = ex + h0 + h1;
    lcur[3][t] = ex + h0 + h1 + h2;
    if (t < NB && tot)
        gbase[t] = t * BSTRIDE + atomicAdd(&bcur[t], tot);
    __syncthreads();
    // pass B: re-read (L2-hot) and scatter into LDS stage, per-wave cursors
    for (int i = t; i < nE; i += 256) {
        int r = rowi[base + i], c = coli[base + i];
        int p = atomicAdd(&lcur[w][c >> SHIFT], 1);
        stage[p] = make_int2(r, c);
    }
    __syncthreads();
    // pass C: coalesced burst write per bucket run (packed, bounds-guarded)
    for (int i = t; i < nE; i += 256) {
        int2 r = stage[i];
        int bb = r.y >> SHIFT;
        int idx = gbase[bb] + (i - excl[bb]);
        if (idx - bb * BSTRIDE < BSTRIDE)   // statistically never false
            recs[idx] = (r.x << SHIFT) | (r.y & 511);
    }
}

// One block per bucket: local histogram -> rowse (absolute spans) + dis,
// LDS scatter of rows, coalesced burst write of srcs (bucket-strided).
__global__ __launch_bounds__(256) void k_fill2(const int* __restrict__ recs,
                                               const int* __restrict__ bcur,
                                               int2* __restrict__ rowse,
                                               float* __restrict__ dis,
                                               int* __restrict__ srcs, int N) {
    __shared__ int hist[512], excl[512], wsum[4];
    __shared__ int srcsL[CAP];
    int t = threadIdx.x;
    int b = blockIdx.x;
    int nbase = b << SHIFT;
    int start = b * BSTRIDE;
    int cnt = min(bcur[b], BSTRIDE);
    int end = start + cnt;
    hist[t] = 0;
    hist[t + 256] = 0;
    __syncthreads();
    for (int i = start + t; i < end; i += 256)
        atomicAdd(&hist[recs[i] & 511], 1);
    __syncthreads();
    int h0 = hist[2 * t], h1 = hist[2 * t + 1];
    int e0 = scan256(h0 + h1, wsum);
    excl[2 * t] = e0;
    excl[2 * t + 1] = e0 + h0;
    int n0 = nbase + 2 * t, n1 = nbase + 2 * t + 1;
    if (n0 < N) {
        rowse[n0] = make_int2(start + e0, start + e0 + h0);
        dis[n0] = rsqrtf((float)(h0 + 1));
    }
    if (n1 < N) {
        rowse[n1] = make_int2(start + e0 + h0, start + e0 + h0 + h1);
        dis[n1] = rsqrtf((float)(h1 + 1));
    }
    __syncthreads();
    if (cnt <= CAP) {
        for (int i = start + t; i < end; i += 256) {
            int r = recs[i];
            int p = atomicAdd(&excl[r & 511], 1);
            srcsL[p] = ((unsigned)r) >> SHIFT;
        }
        __syncthreads();
        for (int i = t; i < cnt; i += 256) srcs[start + i] = srcsL[i];
    } else {  // pathological bucket: direct scatter (correct, slow)
        for (int i = start + t; i < end; i += 256) {
            int r = recs[i];
            int p = atomicAdd(&excl[r & 511], 1);
            srcs[start + p] = ((unsigned)r) >> SHIFT;
        }
    }
}

// Y[M,128] = X[M,128] @ W[128,128] -> f16 (UNSCALED), via MFMA 16x16x32.
// W cols [0,split) from Wa (f32, row stride split), [split,128) from Wb.
// W staged swizzled in LDS then hoisted into 32 f16x8 VGPR B-frags.
// If zcur != nullptr, block 0 zeroes zcur[0..nz) (replaces a memset launch;
// this kernel runs before k_bucket in the stream).
// Verified layouts (learn_hip m89/m120):
//   A[m=lane&15][k=quad*8+j], B[k=quad*8+j][n=lane&15],
//   C/D col=lane&15 row=quad*4+reg.
template <bool XF16>
__global__ __launch_bounds__(256) void k_gemm(const void* __restrict__ Xv,
                                              const float* __restrict__ Wa,
                                              const float* __restrict__ Wb,
                                              int split,
                                              _Float16* __restrict__ Y,
                                              int M, int ngroups,
                                              int* __restrict__ zcur, int nz) {
    __shared__ _Float16 Wl[16384];  // 32 KB swizzled
    int tid = threadIdx.x;
    if (zcur && blockIdx.x == 0 && tid < nz) zcur[tid] = 0;
    int wbs = 128 - split;
    for (int i = tid; i < 16384; i += 256) {
        int k = i >> 7, n = i & 127;
        float v = (n < split) ? Wa[k * split + n] : Wb[k * wbs + (n - split)];
        int tt = n >> 4, c = (k >> 5), q = (k >> 3) & 3, ln = q * 16 + (n & 15);
        Wl[(((tt * 4 + c) * 64) + ln) * 8 + (k & 7)] = (_Float16)v;
    }
    __syncthreads();

    int lane = tid & 63, w = tid >> 6;
    f16x8 B[32];
#pragma unroll
    for (int i = 0; i < 32; i++)
        B[i] = *(const f16x8*)&Wl[(i * 64 + lane) * 8];

    int m16 = lane & 15, quad = lane >> 4;
    for (int g = blockIdx.x; g < ngroups; g += gridDim.x) {
        int rowbase = g * 64 + w * 16;
        if (rowbase >= M) continue;
        int arow = min(rowbase + m16, M - 1);
        f16x8 A[4];
        if (XF16) {
            const _Float16* X = (const _Float16*)Xv;
#pragma unroll
            for (int c = 0; c < 4; c++)
                A[c] = *(const f16x8*)&X[arow * 128 + c * 32 + quad * 8];
        } else {
            const float* X = (const float*)Xv;
#pragma unroll
            for (int c = 0; c < 4; c++) {
                float4 u0 = *(const float4*)&X[arow * 128 + c * 32 + quad * 8];
                float4 u1 = *(const float4*)&X[arow * 128 + c * 32 + quad * 8 + 4];
                f16x8 a;
                a[0] = (_Float16)u0.x; a[1] = (_Float16)u0.y;
                a[2] = (_Float16)u0.z; a[3] = (_Float16)u0.w;
                a[4] = (_Float16)u1.x; a[5] = (_Float16)u1.y;
                a[6] = (_Float16)u1.z; a[7] = (_Float16)u1.w;
                A[c] = a;
            }
        }

        f32x4 acc[8];
#pragma unroll
        for (int t = 0; t < 8; t++) acc[t] = (f32x4)(0.f);
#pragma unroll
        for (int t = 0; t < 8; t++)
#pragma unroll
            for (int c = 0; c < 4; c++)
                acc[t] = __builtin_amdgcn_mfma_f32_16x16x32_f16(
                    A[c], B[t * 4 + c], acc[t], 0, 0, 0);

#pragma unroll
        for (int r = 0; r < 4; r++) {
            int row = rowbase + quad * 4 + r;
            if (row < M) {
#pragma unroll
                for (int t = 0; t < 8; t++)
                    Y[row * 128 + t * 16 + m16] = (_Float16)acc[t][r];
            }
        }
    }
}

// F is UNSCALED f16 [N,128]. out[i] = b + dis_i*(dis_i*F[i] + sum dis_s*F[s]).
// One wave per node; 16 lanes x f16x8 (16B) cover a row; the wave's 4
// lane-groups process 4 edges per trip (1KB/VMEM), main loop 16 edges deep.
// dis[src] applied per-edge (fma; dis is L2-resident). srcs/rowse are
// read-once streams -> nontemporal loads (keep F hot in L2).
// Butterfly (16,32).
// OF16: output f16 [N,128] with relu (layer 1).
// else: mu->outA, lv->outB (f32 [N,64]) + fused z = mu+eps*exp(.5*lv).
template <bool OF16>
__global__ __launch_bounds__(256) void k_agg(const _Float16* __restrict__ F,
                                             const float* __restrict__ dis,
                                             const int* __restrict__ rowse,
                                             const int* __restrict__ srcs,
                                             const float* __restrict__ ba,
                                             const float* __restrict__ bb,
                                             void* __restrict__ outA,
                                             void* __restrict__ outB,
                                             const float* __restrict__ eps,
                                             float* __restrict__ z, int N) {
    int node = blockIdx.x * 4 + (threadIdx.x >> 6);
    if (node >= N) return;
    int lane = threadIdx.x & 63;
    int g = lane >> 4, sl = lane & 15;
    const f16x8* Fr = (const f16x8*)F;   // row r chunk c at Fr[r*16 + c]

    float di = dis[node];
    float acc[8];
#pragma unroll
    for (int j = 0; j < 8; j++) acc[j] = 0.f;
    if (g == 0) {  // self term: dis_i * F[i]
        f16x8 v = Fr[node * 16 + sl];
#pragma unroll
        for (int j = 0; j < 8; j++) acc[j] = di * (float)v[j];
    }

    int s = __builtin_nontemporal_load(&rowse[2 * node]);
    int e = __builtin_nontemporal_load(&rowse[2 * node + 1]);
    int t = s;
    for (; t + 16 <= e; t += 16) {
        int i0 = __builtin_nontemporal_load(&srcs[t + g]);
        int i1 = __builtin_nontemporal_load(&srcs[t + 4 + g]);
        int i2 = __builtin_nontemporal_load(&srcs[t + 8 + g]);
        int i3 = __builtin_nontemporal_load(&srcs[t + 12 + g]);
        float d0 = dis[i0], d1 = dis[i1], d2 = dis[i2], d3 = dis[i3];
        f16x8 v0 = Fr[i0 * 16 + sl];
        f16x8 v1 = Fr[i1 * 16 + sl];
        f16x8 v2 = Fr[i2 * 16 + sl];
        f16x8 v3 = Fr[i3 * 16 + sl];
#pragma unroll
        for (int j = 0; j < 8; j++)
            acc[j] = fmaf(d0, (float)v0[j],
                     fmaf(d1, (float)v1[j],
                     fmaf(d2, (float)v2[j],
                     fmaf(d3, (float)v3[j], acc[j]))));
    }
    if (t + 8 <= e) {
        int i0 = __builtin_nontemporal_load(&srcs[t + g]);
        int i1 = __builtin_nontemporal_load(&srcs[t + 4 + g]);
        float d0 = dis[i0], d1 = dis[i1];
        f16x8 v0 = Fr[i0 * 16 + sl];
        f16x8 v1 = Fr[i1 * 16 + sl];
#pragma unroll
        for (int j = 0; j < 8; j++)
            acc[j] = fmaf(d0, (float)v0[j], fmaf(d1, (float)v1[j], acc[j]));
        t += 8;
    }
    if (t + 4 <= e) {
        int i0 = __builtin_nontemporal_load(&srcs[t + g]);
        float d0 = dis[i0];
        f16x8 v0 = Fr[i0 * 16 + sl];
#pragma unroll
        for (int j = 0; j < 8; j++) acc[j] = fmaf(d0, (float)v0[j], acc[j]);
        t += 4;
    }
    if (t < e) {  // masked tail: 1..3 edges
        int idx = t + g;
        bool ok = idx < e;
        int i0 = ok ? __builtin_nontemporal_load(&srcs[idx]) : 0;
        float d0 = dis[i0];
        f16x8 v0 = Fr[i0 * 16 + sl];
        if (ok) {
#pragma unroll
            for (int j = 0; j < 8; j++) acc[j] = fmaf(d0, (float)v0[j], acc[j]);
        }
    }

    // butterfly reduce over the 4 lane-groups (all lanes end with full sum)
#pragma unroll
    for (int j = 0; j < 8; j++) {
        acc[j] += __shfl_xor(acc[j], 16);
        acc[j] += __shfl_xor(acc[j], 32);
    }

    if constexpr (OF16) {
        float4 b0 = *(const float4*)&ba[sl * 8];
        float4 b1 = *(const float4*)&ba[sl * 8 + 4];
        if (lane < 16) {
            f16x8 o;
            o[0] = (_Float16)fmaxf(fmaf(di, acc[0], b0.x), 0.f);
            o[1] = (_Float16)fmaxf(fmaf(di, acc[1], b0.y), 0.f);
            o[2] = (_Float16)fmaxf(fmaf(di, acc[2], b0.z), 0.f);
            o[3] = (_Float16)fmaxf(fmaf(di, acc[3], b0.w), 0.f);
            o[4] = (_Float16)fmaxf(fmaf(di, acc[4], b1.x), 0.f);
            o[5] = (_Float16)fmaxf(fmaf(di, acc[5], b1.y), 0.f);
            o[6] = (_Float16)fmaxf(fmaf(di, acc[6], b1.z), 0.f);
            o[7] = (_Float16)fmaxf(fmaf(di, acc[7], b1.w), 0.f);
            ((f16x8*)outA)[node * 16 + sl] = o;
        }
    } else {
        // lanes (sl<8): mu cols sl*8..+7 ; lanes (sl>=8): lv cols (sl-8)*8..+7
        const float* bp = (sl < 8) ? ba : bb;
        int cb = (sl & 7) * 8;
        float4 b0 = *(const float4*)&bp[cb];
        float4 b1 = *(const float4*)&bp[cb + 4];
        float o[8];
        o[0] = fmaf(di, acc[0], b0.x);
        o[1] = fmaf(di, acc[1], b0.y);
        o[2] = fmaf(di, acc[2], b0.z);
        o[3] = fmaf(di, acc[3], b0.w);
        o[4] = fmaf(di, acc[4], b1.x);
        o[5] = fmaf(di, acc[5], b1.y);
        o[6] = fmaf(di, acc[6], b1.z);
        o[7] = fmaf(di, acc[7], b1.w);
        if (lane < 16) {
            float* op = (sl < 8) ? (float*)outA : (float*)outB;
            f32x4 s0, s1;
            s0[0] = o[0]; s0[1] = o[1]; s0[2] = o[2]; s0[3] = o[3];
            s1[0] = o[4]; s1[1] = o[5]; s1[2] = o[6]; s1[3] = o[7];
            __builtin_nontemporal_store(s0, (f32x4*)&op[node * 64 + cb]);
            __builtin_nontemporal_store(s1, (f32x4*)&op[node * 64 + cb + 4]);
        }
        // fused reparameterize: lane l (<8) pulls lv chunk from lane l+8
        float lvv[8];
#pragma unroll
        for (int j = 0; j < 8; j++) lvv[j] = __shfl_xor(o[j], 8);
        if (lane < 8) {
            int zb = node * 64 + sl * 8;
            float4 e0 = *(const float4*)&eps[zb];
            float4 e1 = *(const float4*)&eps[zb + 4];
            f32x4 z0, z1;
            z0[0] = fmaf(e0.x, expf(0.5f * lvv[0]), o[0]);
            z0[1] = fmaf(e0.y, expf(0.5f * lvv[1]), o[1]);
            z0[2] = fmaf(e0.z, expf(0.5f * lvv[2]), o[2]);
            z0[3] = fmaf(e0.w, expf(0.5f * lvv[3]), o[3]);
            z1[0] = fmaf(e1.x, expf(0.5f * lvv[4]), o[4]);
            z1[1] = fmaf(e1.y, expf(0.5f * lvv[5]), o[5]);
            z1[2] = fmaf(e1.z, expf(0.5f * lvv[6]), o[6]);
            z1[3] = fmaf(e1.w, expf(0.5f * lvv[7]), o[7]);
            __builtin_nontemporal_store(z0, (f32x4*)&z[zb]);
            __builtin_nontemporal_store(z1, (f32x4*)&z[zb + 4]);
        }
    }
}

extern "C" void kernel_launch(void* const* d_in, const int* in_sizes, int n_in,
                              void* d_out, int out_size, void* d_ws, size_t ws_size,
                              hipStream_t stream) {
    const float* x   = (const float*)d_in[0];
    const int*   ei  = (const int*)d_in[1];
    const float* W1  = (const float*)d_in[2];
    const float* b1  = (const float*)d_in[3];
    const float* Wmu = (const float*)d_in[4];
    const float* bmu = (const float*)d_in[5];
    const float* Wlv = (const float*)d_in[6];
    const float* blv = (const float*)d_in[7];
    const float* eps = (const float*)d_in[8];

    int N = in_sizes[0] / 128;   // 100000
    int E = in_sizes[1] / 2;     // 1600000
    const int* rowi = ei;        // edge_index[0]
    const int* coli = ei + E;    // edge_index[1]
    int NB = (N + (1 << SHIFT) - 1) >> SHIFT;   // 196 buckets

    char* ws = (char*)d_ws;
    size_t off = 0;
    auto alloc = [&](size_t bytes) -> void* {
        void* p = ws + off;
        off += (bytes + 255) & ~(size_t)255;
        return p;
    };
    _Float16* bufA = (_Float16*)alloc((size_t)N * 128 * 2);  // F1, F2
    _Float16* bufB = (_Float16*)alloc((size_t)N * 128 * 2);  // h (f16)
    float* dis    = (float*)alloc((size_t)N * 4);
    int2*  rowse  = (int2*)alloc((size_t)N * 8);
    int*   srcs   = (int*)alloc((size_t)NB * BSTRIDE * 4);
    int*   recs   = (int*)alloc((size_t)NB * BSTRIDE * 4);  // packed row<<9|col
    int*   bcur   = (int*)alloc((size_t)NB * 4);

    float* zo  = (float*)d_out;                 // [N,64]
    float* muo = zo + (size_t)N * 64;           // [N,64]
    float* lvo = zo + (size_t)N * 128;          // [N,64]

    int ngroups = (N + 63) / 64;
    int gblk = ngroups < 640 ? ngroups : 640;
    // F1 = x @ W1 (f16, MFMA); also zeroes bcur for the CSR build.
    k_gemm<false><<<gblk, 256, 0, stream>>>(x, W1, W1, 128, bufA, N, ngroups,
                                            bcur, NB);
    k_bucket<<<(E + EPB - 1) / EPB, 256, 0, stream>>>(rowi, coli, bcur, recs,
                                                      E, NB);
    k_fill2<<<NB, 256, 0, stream>>>(recs, bcur, rowse, dis, srcs, N);
    // h = relu(dis_i*(dis_i*F1[i] + sum dis_s*F1[s]) + b1)   (f16)
    k_agg<true><<<(N + 3) / 4, 256, 0, stream>>>(bufA, dis, (const int*)rowse,
                                                 srcs, b1, b1, bufB, bufB,
                                                 nullptr, nullptr, N);
    // F2 = h @ [Wmu|Wlv]   (f16, MFMA)
    k_gemm<true><<<gblk, 256, 0, stream>>>(bufB, Wmu, Wlv, 64, bufA, N, ngroups,
                                           nullptr, 0);
    // mu/lv = dis-weighted agg + b ; z fused in-wave
    k_agg<false><<<(N + 3) / 4, 256, 0, stream>>>(bufA, dis, (const int*)rowse,
                                                  srcs, bmu, blv, muo, lvo,
                                                  eps, zo, N);
}

// Round 11
// 380.779 us; speedup vs baseline: 2.6588x; 1.0335x over previous
//
#include <hip/hip_runtime.h>
#include <math.h>

// VGAE forward: 3x GCNConv + reparameterize.
// Pipeline (6 dispatches): MFMA GEMM1 (zeroes bcur) -> bucket-sort CSR build
//   (k_bucket fixed-stride + k_fill2) -> agg1(+b1,relu,f16) -> MFMA GEMM2
//   (W_mu|W_lv fused) -> agg2 (f32 mu/lv + fused z).
// R6: k_agg 16B-lane gather; z fused into agg2.
// R7/R10 (REVERTED): dest-side seg-blocking AND feature-panel partitioning
//   both failed to cut agg L2-miss traffic (FETCH pinned ~207MB = NXCD x |F|)
//   and destroyed gather MLP. Agg structure CLOSED at this form (~3.3TB/s
//   fabric rate on random 256B gathers; VALUBusy 54%, occ 75%).
// R9: fixed-stride buckets, per-edge dis, GEMM1 zeroes bcur. 381.5us verified.
// R11/R12 (REVERTED): front-end fusion failed both ways — cooperative launch
//   killed the container (graph-capture hostile); software grid barrier ran
//   at 2.6% VALUBusy / 23% occupancy = 256us vs ~40us of work. CLOSED.
// R13 (REVERTED): NT loads on srcs/rowse streams cost +7us/agg (FETCH
//   207->212MB): sc1-bypass defeats line reuse within the wave's unrolled
//   trip and adds full L2 latency per load. NT is for dead stores only.
// R14: R9 verbatim (verified best).

#define SHIFT 9            // nodes per bucket = 512
#define EPB 2048           // edges per k_bucket block
#define BSTRIDE 12288      // recs/srcs slots per bucket (1.5x Poisson mean)
#define CAP 15104          // fill2 LDS srcs capacity

using f32x4 = __attribute__((ext_vector_type(4))) float;
using f32x2 = __attribute__((ext_vector_type(2))) float;
using f16x8 = __attribute__((ext_vector_type(8))) _Float16;

// Block-wide (256 thr) exclusive scan of one int per thread.
__device__ inline int scan256(int v, int* wsum) {
    __syncthreads();  // protect wsum reuse across calls
    int lane = threadIdx.x & 63, wid = threadIdx.x >> 6;
    int s = v;
#pragma unroll
    for (int d = 1; d < 64; d <<= 1) {
        int u = __shfl_up(s, d, 64);
        if (lane >= d) s += u;
    }
    if (lane == 63) wsum[wid] = s;
    __syncthreads();
    int off = 0;
    for (int w = 0; w < wid; w++) off += wsum[w];
    return off + s - v;
}

// Bin EPB edges into LDS by bucket, burst-write packed (row<<9)|(col&511)
// records into the bucket's fixed-stride region (base = b*BSTRIDE + atomic
// cursor). Two passes over the (L2-hot) chunk; per-wave histograms+cursors.
__global__ __launch_bounds__(256) void k_bucket(const int* __restrict__ rowi,
                                                const int* __restrict__ coli,
                                                int* __restrict__ bcur,
                                                int* __restrict__ recs,
                                                int E, int NB) {
    __shared__ int lh[4][256], lcur[4][256], excl[256], gbase[256], wsum[4];
    __shared__ int2 stage[EPB];
    int t = threadIdx.x, w = t >> 6;
    lh[0][t] = 0; lh[1][t] = 0; lh[2][t] = 0; lh[3][t] = 0;
    __syncthreads();
    int base = blockIdx.x * EPB;
    int nE = min(EPB, E - base);
    // pass A: per-wave histogram
    for (int i = t; i < nE; i += 256)
        atomicAdd(&lh[w][coli[base + i] >> SHIFT], 1);
    __syncthreads();
    int h0 = lh[0][t], h1 = lh[1][t], h2 = lh[2][t], h3 = lh[3][t];
    int tot = h0 + h1 + h2 + h3;
    int ex = scan256(tot, wsum);
    excl[t] = ex;
    lcur[0][t] = ex;
    lcur[1][t] = ex + h0;
    lcur[2][t] = ex + h0 + h1;
    lcur[3][t] = ex + h0 + h1 + h2;
    if (t < NB && tot)
        gbase[t] = t * BSTRIDE + atomicAdd(&bcur[t], tot);
    __syncthreads();
    // pass B: re-read (L2-hot) and scatter into LDS stage, per-wave cursors
    for (int i = t; i < nE; i += 256) {
        int r = rowi[base + i], c = coli[base + i];
        int p = atomicAdd(&lcur[w][c >> SHIFT], 1);
        stage[p] = make_int2(r, c);
    }
    __syncthreads();
    // pass C: coalesced burst write per bucket run (packed, bounds-guarded)
    for (int i = t; i < nE; i += 256) {
        int2 r = stage[i];
        int bb = r.y >> SHIFT;
        int idx = gbase[bb] + (i - excl[bb]);
        if (idx - bb * BSTRIDE < BSTRIDE)   // statistically never false
            recs[idx] = (r.x << SHIFT) | (r.y & 511);
    }
}

// One block per bucket: local histogram -> rowse (absolute spans) + dis,
// LDS scatter of rows, coalesced burst write of srcs (bucket-strided).
__global__ __launch_bounds__(256) void k_fill2(const int* __restrict__ recs,
                                               const int* __restrict__ bcur,
                                               int2* __restrict__ rowse,
                                               float* __restrict__ dis,
                                               int* __restrict__ srcs, int N) {
    __shared__ int hist[512], excl[512], wsum[4];
    __shared__ int srcsL[CAP];
    int t = threadIdx.x;
    int b = blockIdx.x;
    int nbase = b << SHIFT;
    int start = b * BSTRIDE;
    int cnt = min(bcur[b], BSTRIDE);
    int end = start + cnt;
    hist[t] = 0;
    hist[t + 256] = 0;
    __syncthreads();
    for (int i = start + t; i < end; i += 256)
        atomicAdd(&hist[recs[i] & 511], 1);
    __syncthreads();
    int h0 = hist[2 * t], h1 = hist[2 * t + 1];
    int e0 = scan256(h0 + h1, wsum);
    excl[2 * t] = e0;
    excl[2 * t + 1] = e0 + h0;
    int n0 = nbase + 2 * t, n1 = nbase + 2 * t + 1;
    if (n0 < N) {
        rowse[n0] = make_int2(start + e0, start + e0 + h0);
        dis[n0] = rsqrtf((float)(h0 + 1));
    }
    if (n1 < N) {
        rowse[n1] = make_int2(start + e0 + h0, start + e0 + h0 + h1);
        dis[n1] = rsqrtf((float)(h1 + 1));
    }
    __syncthreads();
    if (cnt <= CAP) {
        for (int i = start + t; i < end; i += 256) {
            int r = recs[i];
            int p = atomicAdd(&excl[r & 511], 1);
            srcsL[p] = ((unsigned)r) >> SHIFT;
        }
        __syncthreads();
        for (int i = t; i < cnt; i += 256) srcs[start + i] = srcsL[i];
    } else {  // pathological bucket: direct scatter (correct, slow)
        for (int i = start + t; i < end; i += 256) {
            int r = recs[i];
            int p = atomicAdd(&excl[r & 511], 1);
            srcs[start + p] = ((unsigned)r) >> SHIFT;
        }
    }
}

// Y[M,128] = X[M,128] @ W[128,128] -> f16 (UNSCALED), via MFMA 16x16x32.
// W cols [0,split) from Wa (f32, row stride split), [split,128) from Wb.
// W staged swizzled in LDS then hoisted into 32 f16x8 VGPR B-frags.
// If zcur != nullptr, block 0 zeroes zcur[0..nz) (replaces a memset launch;
// this kernel runs before k_bucket in the stream).
// Verified layouts (learn_hip m89/m120):
//   A[m=lane&15][k=quad*8+j], B[k=quad*8+j][n=lane&15],
//   C/D col=lane&15 row=quad*4+reg.
template <bool XF16>
__global__ __launch_bounds__(256) void k_gemm(const void* __restrict__ Xv,
                                              const float* __restrict__ Wa,
                                              const float* __restrict__ Wb,
                                              int split,
                                              _Float16* __restrict__ Y,
                                              int M, int ngroups,
                                              int* __restrict__ zcur, int nz) {
    __shared__ _Float16 Wl[16384];  // 32 KB swizzled
    int tid = threadIdx.x;
    if (zcur && blockIdx.x == 0 && tid < nz) zcur[tid] = 0;
    int wbs = 128 - split;
    for (int i = tid; i < 16384; i += 256) {
        int k = i >> 7, n = i & 127;
        float v = (n < split) ? Wa[k * split + n] : Wb[k * wbs + (n - split)];
        int tt = n >> 4, c = (k >> 5), q = (k >> 3) & 3, ln = q * 16 + (n & 15);
        Wl[(((tt * 4 + c) * 64) + ln) * 8 + (k & 7)] = (_Float16)v;
    }
    __syncthreads();

    int lane = tid & 63, w = tid >> 6;
    f16x8 B[32];
#pragma unroll
    for (int i = 0; i < 32; i++)
        B[i] = *(const f16x8*)&Wl[(i * 64 + lane) * 8];

    int m16 = lane & 15, quad = lane >> 4;
    for (int g = blockIdx.x; g < ngroups; g += gridDim.x) {
        int rowbase = g * 64 + w * 16;
        if (rowbase >= M) continue;
        int arow = min(rowbase + m16, M - 1);
        f16x8 A[4];
        if (XF16) {
            const _Float16* X = (const _Float16*)Xv;
#pragma unroll
            for (int c = 0; c < 4; c++)
                A[c] = *(const f16x8*)&X[arow * 128 + c * 32 + quad * 8];
        } else {
            const float* X = (const float*)Xv;
#pragma unroll
            for (int c = 0; c < 4; c++) {
                float4 u0 = *(const float4*)&X[arow * 128 + c * 32 + quad * 8];
                float4 u1 = *(const float4*)&X[arow * 128 + c * 32 + quad * 8 + 4];
                f16x8 a;
                a[0] = (_Float16)u0.x; a[1] = (_Float16)u0.y;
                a[2] = (_Float16)u0.z; a[3] = (_Float16)u0.w;
                a[4] = (_Float16)u1.x; a[5] = (_Float16)u1.y;
                a[6] = (_Float16)u1.z; a[7] = (_Float16)u1.w;
                A[c] = a;
            }
        }

        f32x4 acc[8];
#pragma unroll
        for (int t = 0; t < 8; t++) acc[t] = (f32x4)(0.f);
#pragma unroll
        for (int t = 0; t < 8; t++)
#pragma unroll
            for (int c = 0; c < 4; c++)
                acc[t] = __builtin_amdgcn_mfma_f32_16x16x32_f16(
                    A[c], B[t * 4 + c], acc[t], 0, 0, 0);

#pragma unroll
        for (int r = 0; r < 4; r++) {
            int row = rowbase + quad * 4 + r;
            if (row < M) {
#pragma unroll
                for (int t = 0; t < 8; t++)
                    Y[row * 128 + t * 16 + m16] = (_Float16)acc[t][r];
            }
        }
    }
}

// F is UNSCALED f16 [N,128]. out[i] = b + dis_i*(dis_i*F[i] + sum dis_s*F[s]).
// One wave per node; 16 lanes x f16x8 (16B) cover a row; the wave's 4
// lane-groups process 4 edges per trip (1KB/VMEM), main loop 16 edges deep.
// dis[src] applied per-edge (fma; dis is L2-resident). Butterfly (16,32).
// OF16: output f16 [N,128] with relu (layer 1).
// else: mu->outA, lv->outB (f32 [N,64]) + fused z = mu+eps*exp(.5*lv).
template <bool OF16>
__global__ __launch_bounds__(256) void k_agg(const _Float16* __restrict__ F,
                                             const float* __restrict__ dis,
                                             const int2* __restrict__ rowse,
                                             const int* __restrict__ srcs,
                                             const float* __restrict__ ba,
                                             const float* __restrict__ bb,
                                             void* __restrict__ outA,
                                             void* __restrict__ outB,
                                             const float* __restrict__ eps,
                                             float* __restrict__ z, int N) {
    int node = blockIdx.x * 4 + (threadIdx.x >> 6);
    if (node >= N) return;
    int lane = threadIdx.x & 63;
    int g = lane >> 4, sl = lane & 15;
    const f16x8* Fr = (const f16x8*)F;   // row r chunk c at Fr[r*16 + c]

    float di = dis[node];
    float acc[8];
#pragma unroll
    for (int j = 0; j < 8; j++) acc[j] = 0.f;
    if (g == 0) {  // self term: dis_i * F[i]
        f16x8 v = Fr[node * 16 + sl];
#pragma unroll
        for (int j = 0; j < 8; j++) acc[j] = di * (float)v[j];
    }

    int2 se = rowse[node];
    int s = se.x, e = se.y;
    int t = s;
    for (; t + 16 <= e; t += 16) {
        int i0 = srcs[t + g];
        int i1 = srcs[t + 4 + g];
        int i2 = srcs[t + 8 + g];
        int i3 = srcs[t + 12 + g];
        float d0 = dis[i0], d1 = dis[i1], d2 = dis[i2], d3 = dis[i3];
        f16x8 v0 = Fr[i0 * 16 + sl];
        f16x8 v1 = Fr[i1 * 16 + sl];
        f16x8 v2 = Fr[i2 * 16 + sl];
        f16x8 v3 = Fr[i3 * 16 + sl];
#pragma unroll
        for (int j = 0; j < 8; j++)
            acc[j] = fmaf(d0, (float)v0[j],
                     fmaf(d1, (float)v1[j],
                     fmaf(d2, (float)v2[j],
                     fmaf(d3, (float)v3[j], acc[j]))));
    }
    if (t + 8 <= e) {
        int i0 = srcs[t + g];
        int i1 = srcs[t + 4 + g];
        float d0 = dis[i0], d1 = dis[i1];
        f16x8 v0 = Fr[i0 * 16 + sl];
        f16x8 v1 = Fr[i1 * 16 + sl];
#pragma unroll
        for (int j = 0; j < 8; j++)
            acc[j] = fmaf(d0, (float)v0[j], fmaf(d1, (float)v1[j], acc[j]));
        t += 8;
    }
    if (t + 4 <= e) {
        int i0 = srcs[t + g];
        float d0 = dis[i0];
        f16x8 v0 = Fr[i0 * 16 + sl];
#pragma unroll
        for (int j = 0; j < 8; j++) acc[j] = fmaf(d0, (float)v0[j], acc[j]);
        t += 4;
    }
    if (t < e) {  // masked tail: 1..3 edges
        int idx = t + g;
        bool ok = idx < e;
        int i0 = ok ? srcs[idx] : 0;
        float d0 = dis[i0];
        f16x8 v0 = Fr[i0 * 16 + sl];
        if (ok) {
#pragma unroll
            for (int j = 0; j < 8; j++) acc[j] = fmaf(d0, (float)v0[j], acc[j]);
        }
    }

    // butterfly reduce over the 4 lane-groups (all lanes end with full sum)
#pragma unroll
    for (int j = 0; j < 8; j++) {
        acc[j] += __shfl_xor(acc[j], 16);
        acc[j] += __shfl_xor(acc[j], 32);
    }

    if constexpr (OF16) {
        float4 b0 = *(const float4*)&ba[sl * 8];
        float4 b1 = *(const float4*)&ba[sl * 8 + 4];
        if (lane < 16) {
            f16x8 o;
            o[0] = (_Float16)fmaxf(fmaf(di, acc[0], b0.x), 0.f);
            o[1] = (_Float16)fmaxf(fmaf(di, acc[1], b0.y), 0.f);
            o[2] = (_Float16)fmaxf(fmaf(di, acc[2], b0.z), 0.f);
            o[3] = (_Float16)fmaxf(fmaf(di, acc[3], b0.w), 0.f);
            o[4] = (_Float16)fmaxf(fmaf(di, acc[4], b1.x), 0.f);
            o[5] = (_Float16)fmaxf(fmaf(di, acc[5], b1.y), 0.f);
            o[6] = (_Float16)fmaxf(fmaf(di, acc[6], b1.z), 0.f);
            o[7] = (_Float16)fmaxf(fmaf(di, acc[7], b1.w), 0.f);
            ((f16x8*)outA)[node * 16 + sl] = o;
        }
    } else {
        // lanes (sl<8): mu cols sl*8..+7 ; lanes (sl>=8): lv cols (sl-8)*8..+7
        const float* bp = (sl < 8) ? ba : bb;
        int cb = (sl & 7) * 8;
        float4 b0 = *(const float4*)&bp[cb];
        float4 b1 = *(const float4*)&bp[cb + 4];
        float o[8];
        o[0] = fmaf(di, acc[0], b0.x);
        o[1] = fmaf(di, acc[1], b0.y);
        o[2] = fmaf(di, acc[2], b0.z);
        o[3] = fmaf(di, acc[3], b0.w);
        o[4] = fmaf(di, acc[4], b1.x);
        o[5] = fmaf(di, acc[5], b1.y);
        o[6] = fmaf(di, acc[6], b1.z);
        o[7] = fmaf(di, acc[7], b1.w);
        if (lane < 16) {
            float* op = (sl < 8) ? (float*)outA : (float*)outB;
            f32x4 s0, s1;
            s0[0] = o[0]; s0[1] = o[1]; s0[2] = o[2]; s0[3] = o[3];
            s1[0] = o[4]; s1[1] = o[5]; s1[2] = o[6]; s1[3] = o[7];
            __builtin_nontemporal_store(s0, (f32x4*)&op[node * 64 + cb]);
            __builtin_nontemporal_store(s1, (f32x4*)&op[node * 64 + cb + 4]);
        }
        // fused reparameterize: lane l (<8) pulls lv chunk from lane l+8
        float lvv[8];
#pragma unroll
        for (int j = 0; j < 8; j++) lvv[j] = __shfl_xor(o[j], 8);
        if (lane < 8) {
            int zb = node * 64 + sl * 8;
            float4 e0 = *(const float4*)&eps[zb];
            float4 e1 = *(const float4*)&eps[zb + 4];
            f32x4 z0, z1;
            z0[0] = fmaf(e0.x, expf(0.5f * lvv[0]), o[0]);
            z0[1] = fmaf(e0.y, expf(0.5f * lvv[1]), o[1]);
            z0[2] = fmaf(e0.z, expf(0.5f * lvv[2]), o[2]);
            z0[3] = fmaf(e0.w, expf(0.5f * lvv[3]), o[3]);
            z1[0] = fmaf(e1.x, expf(0.5f * lvv[4]), o[4]);
            z1[1] = fmaf(e1.y, expf(0.5f * lvv[5]), o[5]);
            z1[2] = fmaf(e1.z, expf(0.5f * lvv[6]), o[6]);
            z1[3] = fmaf(e1.w, expf(0.5f * lvv[7]), o[7]);
            __builtin_nontemporal_store(z0, (f32x4*)&z[zb]);
            __builtin_nontemporal_store(z1, (f32x4*)&z[zb + 4]);
        }
    }
}

extern "C" void kernel_launch(void* const* d_in, const int* in_sizes, int n_in,
                              void* d_out, int out_size, void* d_ws, size_t ws_size,
                              hipStream_t stream) {
    const float* x   = (const float*)d_in[0];
    const int*   ei  = (const int*)d_in[1];
    const float* W1  = (const float*)d_in[2];
    const float* b1  = (const float*)d_in[3];
    const float* Wmu = (const float*)d_in[4];
    const float* bmu = (const float*)d_in[5];
    const float* Wlv = (const float*)d_in[6];
    const float* blv = (const float*)d_in[7];
    const float* eps = (const float*)d_in[8];

    int N = in_sizes[0] / 128;   // 100000
    int E = in_sizes[1] / 2;     // 1600000
    const int* rowi = ei;        // edge_index[0]
    const int* coli = ei + E;    // edge_index[1]
    int NB = (N + (1 << SHIFT) - 1) >> SHIFT;   // 196 buckets

    char* ws = (char*)d_ws;
    size_t off = 0;
    auto alloc = [&](size_t bytes) -> void* {
        void* p = ws + off;
        off += (bytes + 255) & ~(size_t)255;
        return p;
    };
    _Float16* bufA = (_Float16*)alloc((size_t)N * 128 * 2);  // F1, F2
    _Float16* bufB = (_Float16*)alloc((size_t)N * 128 * 2);  // h (f16)
    float* dis    = (float*)alloc((size_t)N * 4);
    int2*  rowse  = (int2*)alloc((size_t)N * 8);
    int*   srcs   = (int*)alloc((size_t)NB * BSTRIDE * 4);
    int*   recs   = (int*)alloc((size_t)NB * BSTRIDE * 4);  // packed row<<9|col
    int*   bcur   = (int*)alloc((size_t)NB * 4);

    float* zo  = (float*)d_out;                 // [N,64]
    float* muo = zo + (size_t)N * 64;           // [N,64]
    float* lvo = zo + (size_t)N * 128;          // [N,64]

    int ngroups = (N + 63) / 64;
    int gblk = ngroups < 640 ? ngroups : 640;
    // F1 = x @ W1 (f16, MFMA); also zeroes bcur for the CSR build.
    k_gemm<false><<<gblk, 256, 0, stream>>>(x, W1, W1, 128, bufA, N, ngroups,
                                            bcur, NB);
    k_bucket<<<(E + EPB - 1) / EPB, 256, 0, stream>>>(rowi, coli, bcur, recs,
                                                      E, NB);
    k_fill2<<<NB, 256, 0, stream>>>(recs, bcur, rowse, dis, srcs, N);
    // h = relu(dis_i*(dis_i*F1[i] + sum dis_s*F1[s]) + b1)   (f16)
    k_agg<true><<<(N + 3) / 4, 256, 0, stream>>>(bufA, dis, rowse, srcs,
                                                 b1, b1, bufB, bufB,
                                                 nullptr, nullptr, N);
    // F2 = h @ [Wmu|Wlv]   (f16, MFMA)
    k_gemm<true><<<gblk, 256, 0, stream>>>(bufB, Wmu, Wlv, 64, bufA, N, ngroups,
                                           nullptr, 0);
    // mu/lv = dis-weighted agg + b ; z fused in-wave
    k_agg<false><<<(N + 3) / 4, 256, 0, stream>>>(bufA, dis, rowse, srcs,
                                                  bmu, blv, muo, lvo,
                                                  eps, zo, N);
}